// Round 1
// baseline (32.276 us; speedup 1.0000x reference)
//
#include <hip/hip_runtime.h>
#include <math.h>

// Problem constants (match reference setup_inputs)
constexpr int B = 32;
constexpr int C = 1024;
constexpr int T = 1024;
constexpr int N = 3;

// ---------------------------------------------------------------------------
// Kernel 1: compute normalized Cauchy weights f[b][n][t] into workspace.
// grid = B*N blocks, 256 threads; each thread handles 4 t-values.
// ---------------------------------------------------------------------------
__global__ __launch_bounds__(256) void tsf_weights(
    const int* __restrict__ length,
    const float* __restrict__ center,
    const float* __restrict__ gamma_,
    float* __restrict__ f /* [B][N][T] */) {
  const int bn = blockIdx.x;
  const int b = bn / N;
  const int n = bn % N;

  const float c = tanhf(center[n]);
  const float g = tanhf(gamma_[n]);
  const float lf = (float)length[b];
  const float ctr = (lf - 1.0f) * (c + 1.0f) * 0.5f;
  const float gam = expf(1.5f - 2.0f * fabsf(g));
  const float inv_gam = 1.0f / gam;
  const float pref = 1.0f / (3.14159265358979f * gam);

  float vals[4];
  float s = 0.0f;
#pragma unroll
  for (int i = 0; i < 4; ++i) {
    const float t = (float)(threadIdx.x + i * 256);
    const float d = (t - ctr) * inv_gam;
    vals[i] = pref / (1.0f + d * d);
    s += vals[i];
  }

  // wave (64-lane) reduction, then cross-wave via LDS
#pragma unroll
  for (int off = 32; off > 0; off >>= 1) s += __shfl_down(s, off);

  __shared__ float wsum[4];
  const int lane = threadIdx.x & 63;
  const int wv = threadIdx.x >> 6;
  if (lane == 0) wsum[wv] = s;
  __syncthreads();
  const float tot = wsum[0] + wsum[1] + wsum[2] + wsum[3];
  const float inv = 1.0f / (tot + 1e-6f);

  float* frow = f + (size_t)bn * T;
#pragma unroll
  for (int i = 0; i < 4; ++i) frow[threadIdx.x + i * 256] = vals[i] * inv;
}

// ---------------------------------------------------------------------------
// Kernel 2: o[b,c,n] = sum_t f[b,n,t] * v[b,c,t]
// One block per (b, group of CPB channels). f[b] staged in LDS (12 KB).
// Each wave processes one channel row at a time: 64 lanes x 4 float4 loads.
// ---------------------------------------------------------------------------
constexpr int CPB = 16;  // channels per block

__global__ __launch_bounds__(256) void tsf_pool(
    const float* __restrict__ v /* [B][C][T] */,
    const float* __restrict__ f /* [B][N][T] */,
    float* __restrict__ out /* [B][C][N] */) {
  const int groups_per_b = C / CPB;
  const int b = blockIdx.x / groups_per_b;
  const int cg = blockIdx.x % groups_per_b;

  __shared__ float fs[N][T];

  // stage f[b][*][*]: 3072 floats = 768 float4
  {
    const float4* src = (const float4*)(f + (size_t)b * N * T);
    float4* dst = (float4*)(&fs[0][0]);
#pragma unroll
    for (int i = threadIdx.x; i < (N * T) / 4; i += 256) dst[i] = src[i];
  }
  __syncthreads();

  const int lane = threadIdx.x & 63;
  const int wv = threadIdx.x >> 6;

  const float4* w0 = (const float4*)(&fs[0][0]);
  const float4* w1 = (const float4*)(&fs[1][0]);
  const float4* w2 = (const float4*)(&fs[2][0]);

  for (int cc = wv; cc < CPB; cc += 4) {
    const int ch = cg * CPB + cc;
    const float4* row = (const float4*)(v + ((size_t)b * C + ch) * T);

    float a0 = 0.f, a1 = 0.f, a2 = 0.f;
#pragma unroll
    for (int i = lane; i < T / 4; i += 64) {
      const float4 x = row[i];
      const float4 q0 = w0[i];
      const float4 q1 = w1[i];
      const float4 q2 = w2[i];
      a0 += x.x * q0.x + x.y * q0.y + x.z * q0.z + x.w * q0.w;
      a1 += x.x * q1.x + x.y * q1.y + x.z * q1.z + x.w * q1.w;
      a2 += x.x * q2.x + x.y * q2.y + x.z * q2.z + x.w * q2.w;
    }

#pragma unroll
    for (int off = 32; off > 0; off >>= 1) {
      a0 += __shfl_down(a0, off);
      a1 += __shfl_down(a1, off);
      a2 += __shfl_down(a2, off);
    }

    if (lane == 0) {
      float* o = out + ((size_t)b * C + ch) * N;
      o[0] = a0;
      o[1] = a1;
      o[2] = a2;
    }
  }
}

// ---------------------------------------------------------------------------
extern "C" void kernel_launch(void* const* d_in, const int* in_sizes, int n_in,
                              void* d_out, int out_size, void* d_ws,
                              size_t ws_size, hipStream_t stream) {
  const float* video = (const float*)d_in[0];   // (B, C, T, 1, 1) fp32
  const int* length = (const int*)d_in[1];      // (B,) int32
  const float* center = (const float*)d_in[2];  // (N,) fp32
  // d_in[3] = delta (unused by reference)
  const float* gamma_ = (const float*)d_in[4];  // (N,) fp32
  float* out = (float*)d_out;                   // (B, C*N) fp32

  float* f = (float*)d_ws;  // B*N*T floats = 384 KB

  tsf_weights<<<B * N, 256, 0, stream>>>(length, center, gamma_, f);
  tsf_pool<<<B * (C / CPB), 256, 0, stream>>>(video, f, out);
}

// Round 2
// 29.997 us; speedup vs baseline: 1.0760x; 1.0760x over previous
//
#include <hip/hip_runtime.h>
#include <math.h>

// Problem constants (match reference setup_inputs)
constexpr int B = 32;
constexpr int C = 1024;
constexpr int T = 1024;
constexpr int N = 3;
constexpr int CPB = 16;  // channels per block -> grid = 32*64 = 2048 blocks

// ---------------------------------------------------------------------------
// Fused kernel: each block
//   (1) recomputes the normalized Cauchy weights f[b][3][1024] (cheap VALU,
//       redundant across the 64 blocks sharing a batch -- ~3K rcp ops/block),
//   (2) stages them in LDS,
//   (3) streams CPB channel rows of video (float4, coalesced) and produces
//       o[b,c,n] = sum_t f[b,n,t] * v[b,c,t] via wave shuffle reduction.
// One kernel, one dispatch: the 128 MB video read is the only HBM traffic.
// ---------------------------------------------------------------------------
__global__ __launch_bounds__(256) void tsf_fused(
    const float* __restrict__ v /* [B][C][T] */,
    const int* __restrict__ length,
    const float* __restrict__ center,
    const float* __restrict__ gamma_,
    float* __restrict__ out /* [B][C][N] */) {
  const int groups_per_b = C / CPB;
  const int b = blockIdx.x / groups_per_b;
  const int cg = blockIdx.x % groups_per_b;

  __shared__ float fs[N][T];     // 12 KB
  __shared__ float wsum[N][4];   // per-wave partial sums

  const int lane = threadIdx.x & 63;
  const int wv = threadIdx.x >> 6;

  // ---- (1) weight computation: thread handles t = tid, tid+256, ... ----
  const float lf = (float)length[b];

  float vals[N][4];
#pragma unroll
  for (int n = 0; n < N; ++n) {
    const float c = tanhf(center[n]);
    const float g = tanhf(gamma_[n]);
    const float ctr = (lf - 1.0f) * (c + 1.0f) * 0.5f;
    const float gam = expf(1.5f - 2.0f * fabsf(g));
    const float inv_gam = 1.0f / gam;
    const float pref = 1.0f / (3.14159265358979f * gam);

    float s = 0.0f;
#pragma unroll
    for (int i = 0; i < 4; ++i) {
      const float t = (float)(threadIdx.x + i * 256);
      const float d = (t - ctr) * inv_gam;
      vals[n][i] = pref / (1.0f + d * d);
      s += vals[n][i];
    }
    // 64-lane wave reduction of the normalization sum
#pragma unroll
    for (int off = 32; off > 0; off >>= 1) s += __shfl_down(s, off);
    if (lane == 0) wsum[n][wv] = s;
  }
  __syncthreads();

  // ---- (2) normalize into LDS ----
#pragma unroll
  for (int n = 0; n < N; ++n) {
    const float inv =
        1.0f / (wsum[n][0] + wsum[n][1] + wsum[n][2] + wsum[n][3] + 1e-6f);
#pragma unroll
    for (int i = 0; i < 4; ++i)
      fs[n][threadIdx.x + i * 256] = vals[n][i] * inv;
  }
  __syncthreads();

  // ---- (3) pooling: wave -> channel, lanes stride the time axis ----
  const float4* w0 = (const float4*)(&fs[0][0]);
  const float4* w1 = (const float4*)(&fs[1][0]);
  const float4* w2 = (const float4*)(&fs[2][0]);

  for (int cc = wv; cc < CPB; cc += 4) {
    const int ch = cg * CPB + cc;
    const float4* row = (const float4*)(v + ((size_t)b * C + ch) * T);

    float a0 = 0.f, a1 = 0.f, a2 = 0.f;
#pragma unroll
    for (int i = lane; i < T / 4; i += 64) {
      const float4 x = row[i];
      const float4 q0 = w0[i];
      const float4 q1 = w1[i];
      const float4 q2 = w2[i];
      a0 += x.x * q0.x + x.y * q0.y + x.z * q0.z + x.w * q0.w;
      a1 += x.x * q1.x + x.y * q1.y + x.z * q1.z + x.w * q1.w;
      a2 += x.x * q2.x + x.y * q2.y + x.z * q2.z + x.w * q2.w;
    }

#pragma unroll
    for (int off = 32; off > 0; off >>= 1) {
      a0 += __shfl_down(a0, off);
      a1 += __shfl_down(a1, off);
      a2 += __shfl_down(a2, off);
    }

    if (lane == 0) {
      float* o = out + ((size_t)b * C + ch) * N;
      o[0] = a0;
      o[1] = a1;
      o[2] = a2;
    }
  }
}

// ---------------------------------------------------------------------------
extern "C" void kernel_launch(void* const* d_in, const int* in_sizes, int n_in,
                              void* d_out, int out_size, void* d_ws,
                              size_t ws_size, hipStream_t stream) {
  const float* video = (const float*)d_in[0];   // (B, C, T, 1, 1) fp32
  const int* length = (const int*)d_in[1];      // (B,) int32
  const float* center = (const float*)d_in[2];  // (N,) fp32
  // d_in[3] = delta (unused by reference)
  const float* gamma_ = (const float*)d_in[4];  // (N,) fp32
  float* out = (float*)d_out;                   // (B, C*N) fp32

  tsf_fused<<<B * (C / CPB), 256, 0, stream>>>(video, length, center, gamma_,
                                               out);
}